// Round 9
// baseline (586.596 us; speedup 1.0000x reference)
//
#include <hip/hip_runtime.h>
#include <math.h>

#define SQ2PI_F 0.79788456f

typedef __attribute__((ext_vector_type(8))) short short8;
typedef __attribute__((ext_vector_type(4))) float f32x4;
typedef __attribute__((ext_vector_type(4))) unsigned short u16x4;

__device__ inline unsigned short bf16rne(float x) {
  unsigned int u = __float_as_uint(x);
  u += 0x7fffu + ((u >> 16) & 1u);
  return (unsigned short)(u >> 16);
}
__device__ inline float bf2f(unsigned short u) {
  return __uint_as_float(((unsigned int)u) << 16);
}

// ------------------------------------------------------------------
// fused prep: means (+bf16 transposes), zero accumulators, zero loss/frac
// ------------------------------------------------------------------
__global__ void k_prep(const float* __restrict__ w0, const float* __restrict__ w1,
                       const float* __restrict__ w2, const float* __restrict__ wlast,
                       float* __restrict__ m0, float* __restrict__ m1,
                       unsigned short* __restrict__ m1th, float* __restrict__ m2,
                       unsigned short* __restrict__ m2th, float* __restrict__ mlast,
                       float* __restrict__ zbase, float* __restrict__ lf) {
  int b = blockIdx.x, t = threadIdx.x;
  if (b < 784) {
    int i = b * 256 + t;
    m0[i] = tanhf(0.5f * w0[i]);
  } else if (b < 1040) {
    int j = b - 784;
    float v = tanhf(0.5f * w1[j * 256 + t]);
    m1[j * 256 + t] = v;
    m1th[t * 256 + j] = bf16rne(v);   // m1th[r][k] = m1[k][r]
  } else if (b < 1296) {
    int j = b - 1040;
    float v = tanhf(0.5f * w2[j * 256 + t]);
    m2[j * 256 + t] = v;
    m2th[t * 256 + j] = bf16rne(v);   // m2th[i][j] = m2[j][i]
  } else if (b < 1306) {
    int i = (b - 1296) * 256 + t;
    if (i < 2560) mlast[i] = tanhf(0.5f * wlast[i]);
    if (b == 1296 && t < 2) lf[t] = 0.f;
  } else {
    int i = (b - 1306) * 256 + t;
    if (i < 768) zbase[i] = 0.f;
  }
}

// fused column sums: blocks 0..6 m0(112 rows) | 7..10 m1(64) | 11..14 m2(64)
__global__ void k_colsums(const float* __restrict__ m0, const float* __restrict__ m1,
                          const float* __restrict__ m2, float* __restrict__ dsig1,
                          float* __restrict__ s1, float* __restrict__ s2) {
  int b = blockIdx.x, j = threadIdx.x;
  const float* src;
  float* dst;
  int r0, rn;
  if (b < 7) { src = m0; dst = dsig1; r0 = b * 112; rn = r0 + 112; }
  else if (b < 11) { src = m1; dst = s1; r0 = (b - 7) * 64; rn = r0 + 64; }
  else { src = m2; dst = s2; r0 = (b - 11) * 64; rn = r0 + 64; }
  float acc = 0.f;
  for (int i = r0; i < rn; ++i) {
    float v = src[i * 256 + j];
    acc = fmaf(-v, v, acc + 1.0f);
  }
  atomicAdd(&dst[j], acc);
}

// layer 1: block=row r, thread=col j, K=784
__global__ void k_layer1(const float* __restrict__ x, const float* __restrict__ m0,
                         const float* __restrict__ diagsig1, const float* __restrict__ th0,
                         float* __restrict__ x1bar, float* __restrict__ d1) {
  __shared__ float xr[784];
  int r = blockIdx.x, j = threadIdx.x;
  for (int p = j; p < 784; p += 256) xr[p] = x[r * 784 + p];
  __syncthreads();
  float acc = 0.f;
#pragma unroll 8
  for (int k = 0; k < 784; ++k) acc = fmaf(xr[k], m0[k * 256 + j], acc);
  float rs = rsqrtf(diagsig1[j]);
  float xb = tanhf(SQ2PI_F * (acc + th0[j]) * rs);
  x1bar[r * 256 + j] = xb;
  d1[r * 256 + j] = 1.f - xb * xb;
}

// layer-2 pass + h3: x2bar kept in LDS only; emits c2, d2p, h3bar
__global__ void k_layer2(const float* __restrict__ d1, const float* __restrict__ x1bar,
                         const float* __restrict__ m1, const float* __restrict__ m2,
                         const float* __restrict__ s1, const float* __restrict__ th1,
                         const float* __restrict__ th2,
                         float* __restrict__ c2, float* __restrict__ d2p,
                         float* __restrict__ h3bar) {
  __shared__ float sx[256];
  int r = blockIdx.x, i = threadIdx.x;
  float accd = 0.f, acch = 0.f;
  for (int j = 0; j < 256; ++j) {
    float mm = m1[j * 256 + i];
    accd = fmaf(d1[r * 256 + j] * mm, mm, accd);
    acch = fmaf(x1bar[r * 256 + j], mm, acch);
  }
  float rs = rsqrtf(accd + s1[i]);
  float xb = tanhf(SQ2PI_F * (acch + th1[i]) * rs);
  float d = 1.f - xb * xb;
  c2[r * 256 + i] = d * rs;
  d2p[r * 256 + i] = d;
  sx[i] = xb;
  __syncthreads();
  float acch3 = 0.f;
  for (int j = 0; j < 256; ++j)
    acch3 = fmaf(sx[j], m2[j * 256 + i], acch3);
  h3bar[r * 256 + i] = acch3 + th2[i];
}

// ------------------------------------------------------------------
// k_fused<VAR>: identical structure to round 8; VAR is an ABLATION switch:
//  0 = full;  1 = phase-1 only (afX kept live via never-store, early return);
//  2 = loop-B onward only (afX filled by equivalent global loads);
//  3 = full but xcov3 global stores replaced by never-stores (VALU kept).
// `never` is runtime-0 (compiler-opaque) so no ablation path is DCE'd
// while no sink store ever executes.
// ------------------------------------------------------------------
template <int VAR>
__global__ __launch_bounds__(512, 2) void k_fused(
    const unsigned short* __restrict__ m1th, const unsigned short* __restrict__ m2th,
    const float* __restrict__ d1, const float* __restrict__ c2,
    const float* __restrict__ d2p, const float* __restrict__ s1,
    const float* __restrict__ s2, const float* __restrict__ h3bar,
    float* __restrict__ x3bar, float* __restrict__ xcov3,
    int never, float* __restrict__ sink) {
  __shared__ __align__(16) unsigned short TPd[2][8192];  // 2 x 16KB panels
  __shared__ float c2L[256], d2pL[256], s1L[256], s2L[256];
  __shared__ float dsig[256], c3L[256], d3L[256];

  const int b = blockIdx.x;
  const int tid = threadIdx.x;
  const int l = tid & 63, w = tid >> 6;
  const int lr = l & 15, lk = l >> 4;
  const int R = w * 32;

  if (tid < 256) {
    c2L[tid] = c2[b * 256 + tid];
    d2pL[tid] = d2p[b * 256 + tid];
    s1L[tid] = s1[tid];
    s2L[tid] = s2[tid];
  }

  const float* d1b = d1 + b * 256;
  short8 afX[2][8];  // this wave's 32 xcov2 rows

  if (VAR != 2) {
    // hoisted, d1-weighted A-frags for phase 1 (once per block)
    short8 af_w[2][8];
#pragma unroll
    for (int ks = 0; ks < 8; ++ks) {
      f32x4 dv0 = *(const f32x4*)(d1b + ks * 32 + lk * 8);
      f32x4 dv1 = *(const f32x4*)(d1b + ks * 32 + lk * 8 + 4);
#pragma unroll
      for (int f = 0; f < 2; ++f) {
        short8 mv = *(const short8*)(m1th + (size_t)(R + f * 16 + lr) * 256 + ks * 32 + lk * 8);
#pragma unroll
        for (int e = 0; e < 4; ++e) {
          af_w[f][ks][e] = (short)bf16rne(bf2f((unsigned short)mv[e]) * dv0[e]);
          af_w[f][ks][e + 4] = (short)bf16rne(bf2f((unsigned short)mv[e + 4]) * dv1[e]);
        }
      }
    }
    __syncthreads();

    // ---------- phase 1: xcov2 panels, exchange via TPd ----------
#pragma unroll
    for (int cp = 0; cp < 8; ++cp) {
      char* XP = (char*)TPd[cp & 1];
      f32x4 acc[2][2];
#pragma unroll
      for (int i = 0; i < 2; ++i)
#pragma unroll
        for (int j = 0; j < 2; ++j) acc[i][j] = {0.f, 0.f, 0.f, 0.f};
#pragma unroll
      for (int ks = 0; ks < 8; ++ks) {
        short8 bq[2];
#pragma unroll
        for (int f = 0; f < 2; ++f)
          bq[f] = *(const short8*)(m1th + (size_t)(cp * 32 + f * 16 + lr) * 256 + ks * 32 + lk * 8);
#pragma unroll
        for (int i = 0; i < 2; ++i)
#pragma unroll
          for (int j = 0; j < 2; ++j)
            acc[i][j] = __builtin_amdgcn_mfma_f32_16x16x32_bf16(af_w[i][ks], bq[j], acc[i][j], 0, 0, 0);
      }
      // epilogue -> XP transposed (xcov2 symmetric)
#pragma unroll
      for (int i = 0; i < 2; ++i) {
        int r0 = R + i * 16 + lk * 4;
#pragma unroll
        for (int j = 0; j < 2; ++j) {
          int p = j * 16 + lr;
          int cc = cp * 32 + p;
          float c2c = c2L[cc];
          u16x4 st;
#pragma unroll
          for (int e = 0; e < 4; ++e) {
            int r = r0 + e;
            float g = acc[i][j][e];
            if (r == cc) g += s1L[r];
            float v = SQ2PI_F * c2L[r] * c2c * g;
            if (r == cc) v += d2pL[r];
            st[e] = bf16rne(v);
          }
          *(u16x4*)(XP + (p << 9) + (((unsigned)(r0 << 1)) ^ ((p & 7) << 4))) = st;
        }
      }
      __syncthreads();
      if (w == cp) {
#pragma unroll
        for (int f = 0; f < 2; ++f) {
          int p2 = f * 16 + lr;
#pragma unroll
          for (int ks = 0; ks < 8; ++ks)
            afX[f][ks] = *(const short8*)(XP + (p2 << 9) + (((unsigned)(ks * 64 + lk * 16)) ^ ((p2 & 7) << 4)));
        }
      }
    }
  } else {
    // VAR==2: skip phase 1; fill afX with equivalent-cost global loads
    __syncthreads();
#pragma unroll
    for (int f = 0; f < 2; ++f)
#pragma unroll
      for (int ks = 0; ks < 8; ++ks)
        afX[f][ks] = *(const short8*)(m1th + (size_t)(R + f * 16 + lr) * 256 + ks * 32 + lk * 8);
    __syncthreads();
  }

  if (VAR == 1) {
    if (never) {
#pragma unroll
      for (int f = 0; f < 2; ++f)
#pragma unroll
        for (int ks = 0; ks < 8; ++ks)
          *(short8*)((char*)sink + (f * 8 + ks) * 16 + tid) = afX[f][ks];
    }
    return;
  }

  // ---------- loop B: pipelined t3-panel / sigma3 accumulation ----------
  f32x4 sig[8][2][2];
#pragma unroll
  for (int lp = 0; lp < 8; ++lp)
#pragma unroll
    for (int i = 0; i < 2; ++i)
#pragma unroll
      for (int j = 0; j < 2; ++j) sig[lp][i][j] = {0.f, 0.f, 0.f, 0.f};

#define STEP1(LP)                                                                          \
  {                                                                                        \
    char* TB = (char*)TPd[(LP) & 1];                                                       \
    f32x4 at[2][2];                                                                        \
    _Pragma("unroll") for (int i = 0; i < 2; ++i) _Pragma("unroll")                        \
        for (int j = 0; j < 2; ++j) at[i][j] = {0.f, 0.f, 0.f, 0.f};                       \
    _Pragma("unroll") for (int ks = 0; ks < 8; ++ks) {                                     \
      short8 bq[2];                                                                        \
      _Pragma("unroll") for (int f = 0; f < 2; ++f) bq[f] =                                \
          *(const short8*)(m2th + (size_t)((LP)*32 + f * 16 + lr) * 256 + ks * 32 + lk * 8); \
      _Pragma("unroll") for (int i = 0; i < 2; ++i) _Pragma("unroll")                      \
          for (int j = 0; j < 2; ++j) at[i][j] =                                           \
              __builtin_amdgcn_mfma_f32_16x16x32_bf16(afX[i][ks], bq[j], at[i][j], 0, 0, 0); \
    }                                                                                      \
    _Pragma("unroll") for (int i = 0; i < 2; ++i) {                                        \
      int j0 = R + i * 16 + lk * 4;                                                        \
      _Pragma("unroll") for (int jf = 0; jf < 2; ++jf) {                                   \
        int p = jf * 16 + lr;                                                              \
        u16x4 st;                                                                          \
        _Pragma("unroll") for (int e = 0; e < 4; ++e) st[e] = bf16rne(at[i][jf][e]);       \
        *(u16x4*)(TB + (p << 9) + (((unsigned)(j0 << 1)) ^ ((p & 7) << 4))) = st;          \
      }                                                                                    \
    }                                                                                      \
  }

#define STEP2(LP)                                                                          \
  {                                                                                        \
    const char* TB = (const char*)TPd[(LP) & 1];                                           \
    _Pragma("unroll") for (int ks = 0; ks < 8; ++ks) {                                     \
      short8 a2[2], bq2[2];                                                                \
      _Pragma("unroll") for (int f = 0; f < 2; ++f) {                                      \
        a2[f] = *(const short8*)(m2th + (size_t)(R + f * 16 + lr) * 256 + ks * 32 + lk * 8); \
        int p = f * 16 + lr;                                                               \
        bq2[f] = *(const short8*)(TB + (p << 9) +                                          \
                                  (((unsigned)(ks * 64 + lk * 16)) ^ ((p & 7) << 4)));     \
      }                                                                                    \
      _Pragma("unroll") for (int i = 0; i < 2; ++i) _Pragma("unroll")                      \
          for (int j = 0; j < 2; ++j) sig[LP][i][j] =                                      \
              __builtin_amdgcn_mfma_f32_16x16x32_bf16(a2[i], bq2[j], sig[LP][i][j], 0, 0, 0); \
    }                                                                                      \
    if (w == (LP) && lk == (lr >> 2)) {                                                    \
      _Pragma("unroll") for (int lf = 0; lf < 2; ++lf) {                                   \
        f32x4 v4 = sig[LP][lf][lf];                                                        \
        dsig[R + lf * 16 + lr] = v4[lr & 3];                                               \
      }                                                                                    \
    }                                                                                      \
  }

  STEP1(0)
  __syncthreads();
  STEP1(1) STEP2(0)
  __syncthreads();
  STEP1(2) STEP2(1)
  __syncthreads();
  STEP1(3) STEP2(2)
  __syncthreads();
  STEP1(4) STEP2(3)
  __syncthreads();
  STEP1(5) STEP2(4)
  __syncthreads();
  STEP1(6) STEP2(5)
  __syncthreads();
  STEP1(7) STEP2(6)
  __syncthreads();
  STEP2(7)
  __syncthreads();
#undef STEP1
#undef STEP2

  // ---------- c3 phase ----------
  if (tid < 256) {
    float ds = dsig[tid] + s2L[tid];
    float rs = rsqrtf(ds);
    float xb = tanhf(SQ2PI_F * h3bar[b * 256 + tid] * rs);
    x3bar[b * 256 + tid] = xb;
    float d = 1.f - xb * xb;
    c3L[tid] = d * rs;
    d3L[tid] = d;
  }
  __syncthreads();

  // ---------- epilogue: xcov3 from sig (transposed-symmetric store) ----------
#pragma unroll
  for (int lp = 0; lp < 8; ++lp) {
#pragma unroll
    for (int ifg = 0; ifg < 2; ++ifg) {
      int i0 = R + ifg * 16 + lk * 4;
#pragma unroll
      for (int lf = 0; lf < 2; ++lf) {
        int gl = lp * 32 + lf * 16 + lr;
        float cg = c3L[gl];
        f32x4 st;
#pragma unroll
        for (int e = 0; e < 4; ++e) {
          int i = i0 + e;
          float g = sig[lp][ifg][lf][e];
          if (i == gl) g += s2L[i];
          float v = SQ2PI_F * c3L[i] * cg * g;
          if (i == gl) v += d3L[i];
          st[e] = v;
        }
        if (VAR == 3) {
          if (never) *(f32x4*)((char*)sink + ((lp * 4 + ifg * 2 + lf) << 4) + tid) = st;
        } else {
          *(f32x4*)(xcov3 + ((size_t)b << 16) + (size_t)gl * 256 + i0) = st;
        }
      }
    }
  }
}

// final layer + log_softmax + loss + frac_correct. grid 4 x block 64
__global__ void k_final4(const float* __restrict__ x3bar, const float* __restrict__ mlast,
                         const float* __restrict__ thlast, const int* __restrict__ target,
                         float* __restrict__ hlast_out, float* __restrict__ logp_out,
                         float* __restrict__ loss_out, float* __restrict__ frac_out) {
  __shared__ float Wl[2560];
  int t = threadIdx.x;
  int r = blockIdx.x * 64 + t;
  for (int p = t; p < 2560; p += 64) Wl[p] = mlast[p];
  __syncthreads();
  float acc[10];
#pragma unroll
  for (int c = 0; c < 10; ++c) acc[c] = thlast[c];
  for (int j = 0; j < 256; ++j) {
    float xv = x3bar[r * 256 + j];
#pragma unroll
    for (int c = 0; c < 10; ++c) acc[c] = fmaf(xv, Wl[j * 10 + c], acc[c]);
  }
#pragma unroll
  for (int c = 0; c < 10; ++c) hlast_out[r * 10 + c] = acc[c];
  float mx = acc[0];
  int am = 0;
#pragma unroll
  for (int c = 1; c < 10; ++c)
    if (acc[c] > mx) { mx = acc[c]; am = c; }
  float se = 0.f;
#pragma unroll
  for (int c = 0; c < 10; ++c) se += expf(acc[c] - mx);
  float lse = logf(se);
#pragma unroll
  for (int c = 0; c < 10; ++c) logp_out[r * 10 + c] = acc[c] - mx - lse;
  int tg = target[r];
  float lossc = -(acc[tg] - mx - lse) * (1.f / 256.f);
  float corr = (am == tg) ? (1.f / 256.f) : 0.f;
#pragma unroll
  for (int off = 32; off > 0; off >>= 1) {
    lossc += __shfl_down(lossc, off);
    corr += __shfl_down(corr, off);
  }
  if (t == 0) {
    atomicAdd(loss_out, lossc);
    atomicAdd(frac_out, corr);
  }
}

// ------------------------------------------------------------------

extern "C" void kernel_launch(void* const* d_in, const int* in_sizes, int n_in,
                              void* d_out, int out_size, void* d_ws, size_t ws_size,
                              hipStream_t stream) {
  const float* x = (const float*)d_in[0];
  const int* target = (const int*)d_in[1];
  const float* w0 = (const float*)d_in[2];
  const float* w1 = (const float*)d_in[3];
  const float* w2 = (const float*)d_in[4];
  const float* wlast = (const float*)d_in[5];
  const float* th0 = (const float*)d_in[6];
  const float* th1 = (const float*)d_in[7];
  const float* th2 = (const float*)d_in[8];
  const float* thlast = (const float*)d_in[9];

  float* W = (float*)d_ws;
  size_t o = 0;
  auto alloc = [&](size_t n) { float* p = W + o; o += n; return p; };
  float* m0 = alloc(200704);
  float* m1 = alloc(65536);
  float* m2 = alloc(65536);
  float* mlast = alloc(2560);
  float* diagsig1 = alloc(256);  // zero-block start (768 floats, contiguous)
  float* s1 = alloc(256);
  float* s2 = alloc(256);
  float* x1bar = alloc(65536);
  float* d1 = alloc(65536);
  float* c2 = alloc(65536);
  float* d2p = alloc(65536);
  float* h3bar = alloc(65536);
  float* x3bar = alloc(65536);
  unsigned short* m1th = (unsigned short*)alloc(32768);  // 65536 bf16
  unsigned short* m2th = (unsigned short*)alloc(32768);  // 65536 bf16

  float* hlast = (float*)d_out;
  float* logp = hlast + 2560;
  float* xcov3_out = logp + 2560;
  float* loss = xcov3_out + 16777216;
  float* frac = loss + 1;

  // 1) prep
  k_prep<<<1309, 256, 0, stream>>>(w0, w1, w2, wlast, m0, m1, m1th, m2, m2th,
                                   mlast, diagsig1, loss);
  // 2) column sums
  k_colsums<<<15, 256, 0, stream>>>(m0, m1, m2, diagsig1, s1, s2);
  // 3) layer 1
  k_layer1<<<256, 256, 0, stream>>>(x, m0, diagsig1, th0, x1bar, d1);
  // 4) layer 2 (+h3)
  k_layer2<<<256, 256, 0, stream>>>(d1, x1bar, m1, m2, s1, th1, th2, c2, d2p, h3bar);

  // 5a) ABLATION probes (outputs overwritten by the real run below; never=0)
  k_fused<0><<<256, 512, 0, stream>>>(m1th, m2th, d1, c2, d2p, s1, s2, h3bar,
                                      x3bar, xcov3_out, 0, xcov3_out);
  k_fused<1><<<256, 512, 0, stream>>>(m1th, m2th, d1, c2, d2p, s1, s2, h3bar,
                                      x3bar, xcov3_out, 0, xcov3_out);
  k_fused<2><<<256, 512, 0, stream>>>(m1th, m2th, d1, c2, d2p, s1, s2, h3bar,
                                      x3bar, xcov3_out, 0, xcov3_out);
  k_fused<3><<<256, 512, 0, stream>>>(m1th, m2th, d1, c2, d2p, s1, s2, h3bar,
                                      x3bar, xcov3_out, 0, xcov3_out);

  // 5b) REAL fused sigma-chain (last: overwrites all probe output)
  k_fused<0><<<256, 512, 0, stream>>>(m1th, m2th, d1, c2, d2p, s1, s2, h3bar,
                                      x3bar, xcov3_out, 0, xcov3_out);

  // 6) final layer + softmax + loss + acc
  k_final4<<<4, 64, 0, stream>>>(x3bar, mlast, thlast, target, hlast, logp, loss, frac);
}

// Round 10
// 156.311 us; speedup vs baseline: 3.7527x; 3.7527x over previous
//
#include <hip/hip_runtime.h>
#include <math.h>

#define SQ2PI_F 0.79788456f

typedef __attribute__((ext_vector_type(8))) short short8;
typedef __attribute__((ext_vector_type(4))) float f32x4;
typedef __attribute__((ext_vector_type(4))) unsigned short u16x4;
typedef __attribute__((address_space(1))) unsigned int gas_u32;
typedef __attribute__((address_space(3))) unsigned int las_u32;

__device__ inline unsigned short bf16rne(float x) {
  unsigned int u = __float_as_uint(x);
  u += 0x7fffu + ((u >> 16) & 1u);
  return (unsigned short)(u >> 16);
}
__device__ inline float bf2f(unsigned short u) {
  return __uint_as_float(((unsigned int)u) << 16);
}

// ------------------------------------------------------------------
// fused prep: means (+bf16 transposes), zero accumulators, zero loss/frac
// ------------------------------------------------------------------
__global__ void k_prep(const float* __restrict__ w0, const float* __restrict__ w1,
                       const float* __restrict__ w2, const float* __restrict__ wlast,
                       float* __restrict__ m0, float* __restrict__ m1,
                       unsigned short* __restrict__ m1th, float* __restrict__ m2,
                       unsigned short* __restrict__ m2th, float* __restrict__ mlast,
                       float* __restrict__ zbase, float* __restrict__ lf) {
  int b = blockIdx.x, t = threadIdx.x;
  if (b < 784) {
    int i = b * 256 + t;
    m0[i] = tanhf(0.5f * w0[i]);
  } else if (b < 1040) {
    int j = b - 784;
    float v = tanhf(0.5f * w1[j * 256 + t]);
    m1[j * 256 + t] = v;
    m1th[t * 256 + j] = bf16rne(v);   // m1th[r][k] = m1[k][r]
  } else if (b < 1296) {
    int j = b - 1040;
    float v = tanhf(0.5f * w2[j * 256 + t]);
    m2[j * 256 + t] = v;
    m2th[t * 256 + j] = bf16rne(v);   // m2th[i][j] = m2[j][i]
  } else if (b < 1306) {
    int i = (b - 1296) * 256 + t;
    if (i < 2560) mlast[i] = tanhf(0.5f * wlast[i]);
    if (b == 1296 && t < 2) lf[t] = 0.f;
  } else {
    int i = (b - 1306) * 256 + t;
    if (i < 768) zbase[i] = 0.f;
  }
}

// fused column sums: blocks 0..6 m0(112 rows) | 7..10 m1(64) | 11..14 m2(64)
__global__ void k_colsums(const float* __restrict__ m0, const float* __restrict__ m1,
                          const float* __restrict__ m2, float* __restrict__ dsig1,
                          float* __restrict__ s1, float* __restrict__ s2) {
  int b = blockIdx.x, j = threadIdx.x;
  const float* src;
  float* dst;
  int r0, rn;
  if (b < 7) { src = m0; dst = dsig1; r0 = b * 112; rn = r0 + 112; }
  else if (b < 11) { src = m1; dst = s1; r0 = (b - 7) * 64; rn = r0 + 64; }
  else { src = m2; dst = s2; r0 = (b - 11) * 64; rn = r0 + 64; }
  float acc = 0.f;
  for (int i = r0; i < rn; ++i) {
    float v = src[i * 256 + j];
    acc = fmaf(-v, v, acc + 1.0f);
  }
  atomicAdd(&dst[j], acc);
}

// layer 1: block=row r, 512 threads split-k (h=0: k<392, h=1: k>=392)
__global__ void k_layer1(const float* __restrict__ x, const float* __restrict__ m0,
                         const float* __restrict__ diagsig1, const float* __restrict__ th0,
                         float* __restrict__ x1bar, float* __restrict__ d1) {
  __shared__ float xr[784];
  __shared__ float part[256];
  int r = blockIdx.x, t = threadIdx.x;
  int j = t & 255, h = t >> 8;
  for (int p = t; p < 784; p += 512) xr[p] = x[r * 784 + p];
  __syncthreads();
  float acc = 0.f;
  int k0 = h * 392, k1 = k0 + 392;
#pragma unroll 8
  for (int k = k0; k < k1; ++k) acc = fmaf(xr[k], m0[k * 256 + j], acc);
  if (h) part[j] = acc;
  __syncthreads();
  if (!h) {
    acc += part[j];
    float rs = rsqrtf(diagsig1[j]);
    float xb = tanhf(SQ2PI_F * (acc + th0[j]) * rs);
    x1bar[r * 256 + j] = xb;
    d1[r * 256 + j] = 1.f - xb * xb;
  }
}

// layer-2 pass + h3, 512 threads split-k
__global__ void k_layer2(const float* __restrict__ d1, const float* __restrict__ x1bar,
                         const float* __restrict__ m1, const float* __restrict__ m2,
                         const float* __restrict__ s1, const float* __restrict__ th1,
                         const float* __restrict__ th2,
                         float* __restrict__ c2, float* __restrict__ d2p,
                         float* __restrict__ h3bar) {
  __shared__ float pd[256], ph[256], sx[256], p3[256];
  int r = blockIdx.x, t = threadIdx.x;
  int i = t & 255, h = t >> 8;
  int j0 = h * 128, j1 = j0 + 128;
  float accd = 0.f, acch = 0.f;
  for (int j = j0; j < j1; ++j) {
    float mm = m1[j * 256 + i];
    accd = fmaf(d1[r * 256 + j] * mm, mm, accd);
    acch = fmaf(x1bar[r * 256 + j], mm, acch);
  }
  if (h) { pd[i] = accd; ph[i] = acch; }
  __syncthreads();
  if (!h) {
    accd += pd[i];
    acch += ph[i];
    float rs = rsqrtf(accd + s1[i]);
    float xb = tanhf(SQ2PI_F * (acch + th1[i]) * rs);
    float d = 1.f - xb * xb;
    c2[r * 256 + i] = d * rs;
    d2p[r * 256 + i] = d;
    sx[i] = xb;
  }
  __syncthreads();
  float acc3 = 0.f;
  for (int j = j0; j < j1; ++j) acc3 = fmaf(sx[j], m2[j * 256 + i], acc3);
  if (h) p3[i] = acc3;
  __syncthreads();
  if (!h) h3bar[r * 256 + i] = acc3 + p3[i] + th2[i];
}

// ------------------------------------------------------------------
// k_fused: one block (512 thr / 8 waves) per batch. All in-loop weight
// operands arrive via global_load_lds staged panels (double-buffered,
// prefetched one segment ahead); loop-invariant fragments (af_w, afX,
// am2) live in registers. Zero per-lane global loads inside the loops.
// Staged-panel layout (rule 21): LDS[row][ch] = G[row][ch ^ (row&7)],
// so reads use chunk (kc ^ (row&7)) -> same XOR pattern as XB panels.
// MFMA frags: A [row][k] lr=row; B [col][k] lr=col; C rows lk*4+e, cols lr.
// ------------------------------------------------------------------
__global__ __launch_bounds__(512, 2) void k_fused(
    const unsigned short* __restrict__ m1th, const unsigned short* __restrict__ m2th,
    const float* __restrict__ d1, const float* __restrict__ c2,
    const float* __restrict__ d2p, const float* __restrict__ s1,
    const float* __restrict__ s2, const float* __restrict__ h3bar,
    float* __restrict__ x3bar, float* __restrict__ xcov3) {
  __shared__ __align__(16) unsigned short SB[2][8192];  // staged weight panels
  __shared__ __align__(16) unsigned short XB[2][8192];  // exchange panels
  __shared__ float c2L[256], d2pL[256], s1L[256], s2L[256];
  __shared__ float dsig[256], c3L[256], d3L[256];

  const int b = blockIdx.x;
  const int tid = threadIdx.x;
  const int l = tid & 63, w = tid >> 6;
  const int lr = l & 15, lk = l >> 4;
  const int R = w * 32;

  // stage one 32x256 bf16 panel (16KB): 2 gload_lds x16B per lane.
  // dst is wave-uniform (+lane*16B by HW); source chunk inverse-swizzled.
  auto stage_panel = [&](const unsigned short* gsrc, unsigned short* sb) {
#pragma unroll
    for (int q = 0; q < 2; ++q) {
      int rl = q * 16 + w * 2 + (l >> 5);
      int ch = l & 31;
      const unsigned short* src = gsrc + rl * 256 + ((ch ^ (rl & 7)) << 3);
      unsigned short* dst = sb + (q * 16 + w * 2) * 256;
      __builtin_amdgcn_global_load_lds((const gas_u32*)src, (las_u32*)dst, 16, 0, 0);
    }
  };

// read short8 at panel row p (0..31), k-chunk kc (=ks*4+lk)
#define PREAD(SBASE, p, kc)                                   \
  (*(const short8*)((const char*)(SBASE) + ((p) << 9) +      \
                    ((unsigned)((((kc) ^ ((p) & 7))) << 4))))

  // kick off panel-0 staging immediately (latency hides under hoists)
  stage_panel(m1th, SB[0]);

  if (tid < 256) {
    c2L[tid] = c2[b * 256 + tid];
    d2pL[tid] = d2p[b * 256 + tid];
    s1L[tid] = s1[tid];
    s2L[tid] = s2[tid];
  }

  const float* d1b = d1 + b * 256;

  // hoisted, d1-weighted phase-1 A-frags (per-lane, once per block)
  short8 af_w[2][8];
#pragma unroll
  for (int ks = 0; ks < 8; ++ks) {
    f32x4 dv0 = *(const f32x4*)(d1b + ks * 32 + lk * 8);
    f32x4 dv1 = *(const f32x4*)(d1b + ks * 32 + lk * 8 + 4);
#pragma unroll
    for (int f = 0; f < 2; ++f) {
      short8 mv = *(const short8*)(m1th + (size_t)(R + f * 16 + lr) * 256 + ks * 32 + lk * 8);
#pragma unroll
      for (int e = 0; e < 4; ++e) {
        af_w[f][ks][e] = (short)bf16rne(bf2f((unsigned short)mv[e]) * dv0[e]);
        af_w[f][ks][e + 4] = (short)bf16rne(bf2f((unsigned short)mv[e + 4]) * dv1[e]);
      }
    }
  }
  __syncthreads();  // drains gload_lds (SB[0]) + c2L visibility

  short8 afX[2][8];  // this wave's 32 xcov2 rows (filled at cp == w)

  // ---------- phase 1: xcov2 panels from staged m1th, exchange via XB ----------
#pragma unroll
  for (int cp = 0; cp < 8; ++cp) {
    if (cp < 7)
      stage_panel(m1th + (size_t)(cp + 1) * 32 * 256, SB[(cp + 1) & 1]);
    else
      stage_panel(m2th, SB[0]);  // prologue panel for loop B
    const unsigned short* sbc = SB[cp & 1];
    f32x4 acc[2][2];
#pragma unroll
    for (int i = 0; i < 2; ++i)
#pragma unroll
      for (int j = 0; j < 2; ++j) acc[i][j] = {0.f, 0.f, 0.f, 0.f};
#pragma unroll
    for (int ks = 0; ks < 8; ++ks) {
      short8 bq[2];
#pragma unroll
      for (int f = 0; f < 2; ++f) bq[f] = PREAD(sbc, f * 16 + lr, ks * 4 + lk);
#pragma unroll
      for (int i = 0; i < 2; ++i)
#pragma unroll
        for (int j = 0; j < 2; ++j)
          acc[i][j] = __builtin_amdgcn_mfma_f32_16x16x32_bf16(af_w[i][ks], bq[j], acc[i][j], 0, 0, 0);
    }
    // epilogue -> XB transposed (xcov2 symmetric)
    char* XP = (char*)XB[cp & 1];
#pragma unroll
    for (int i = 0; i < 2; ++i) {
      int r0 = R + i * 16 + lk * 4;
#pragma unroll
      for (int j = 0; j < 2; ++j) {
        int p = j * 16 + lr;
        int cc = cp * 32 + p;
        float c2c = c2L[cc];
        u16x4 st;
#pragma unroll
        for (int e = 0; e < 4; ++e) {
          int r = r0 + e;
          float g = acc[i][j][e];
          if (r == cc) g += s1L[r];
          float v = SQ2PI_F * c2L[r] * c2c * g;
          if (r == cc) v += d2pL[r];
          st[e] = bf16rne(v);
        }
        *(u16x4*)(XP + (p << 9) + (((unsigned)(r0 << 1)) ^ ((p & 7) << 4))) = st;
      }
    }
    __syncthreads();
    if (w == cp) {
#pragma unroll
      for (int f = 0; f < 2; ++f) {
        int p2 = f * 16 + lr;
#pragma unroll
        for (int ks = 0; ks < 8; ++ks)
          afX[f][ks] = PREAD(XP, p2, ks * 4 + lk);
      }
    }
  }

  // hoist wave's own 32 m2th rows (STEP2 A-operand; loop-invariant)
  short8 am2[2][8];
#pragma unroll
  for (int f = 0; f < 2; ++f)
#pragma unroll
    for (int ks = 0; ks < 8; ++ks)
      am2[f][ks] = *(const short8*)(m2th + (size_t)(R + f * 16 + lr) * 256 + ks * 32 + lk * 8);

  // ---------- loop B: pipelined t3-panel / sigma3 accumulation ----------
  f32x4 sig[8][2][2];
#pragma unroll
  for (int lp = 0; lp < 8; ++lp)
#pragma unroll
    for (int i = 0; i < 2; ++i)
#pragma unroll
      for (int j = 0; j < 2; ++j) sig[lp][i][j] = {0.f, 0.f, 0.f, 0.f};

#define STAGE2(N) stage_panel(m2th + (size_t)(N) * 32 * 256, SB[(N) & 1]);

#define STEP1(LP)                                                                          \
  {                                                                                        \
    const unsigned short* sb1 = SB[(LP) & 1];                                              \
    char* TB = (char*)XB[(LP) & 1];                                                        \
    f32x4 at[2][2];                                                                        \
    _Pragma("unroll") for (int i = 0; i < 2; ++i) _Pragma("unroll")                        \
        for (int j = 0; j < 2; ++j) at[i][j] = {0.f, 0.f, 0.f, 0.f};                       \
    _Pragma("unroll") for (int ks = 0; ks < 8; ++ks) {                                     \
      short8 bq[2];                                                                        \
      _Pragma("unroll") for (int f = 0; f < 2; ++f)                                        \
          bq[f] = PREAD(sb1, f * 16 + lr, ks * 4 + lk);                                    \
      _Pragma("unroll") for (int i = 0; i < 2; ++i) _Pragma("unroll")                      \
          for (int j = 0; j < 2; ++j) at[i][j] =                                           \
              __builtin_amdgcn_mfma_f32_16x16x32_bf16(afX[i][ks], bq[j], at[i][j], 0, 0, 0); \
    }                                                                                      \
    _Pragma("unroll") for (int i = 0; i < 2; ++i) {                                        \
      int j0 = R + i * 16 + lk * 4;                                                        \
      _Pragma("unroll") for (int jf = 0; jf < 2; ++jf) {                                   \
        int p = jf * 16 + lr;                                                              \
        u16x4 st;                                                                          \
        _Pragma("unroll") for (int e = 0; e < 4; ++e) st[e] = bf16rne(at[i][jf][e]);       \
        *(u16x4*)(TB + (p << 9) + (((unsigned)(j0 << 1)) ^ ((p & 7) << 4))) = st;          \
      }                                                                                    \
    }                                                                                      \
  }

#define STEP2(LP)                                                                          \
  {                                                                                        \
    const char* TB = (const char*)XB[(LP) & 1];                                            \
    _Pragma("unroll") for (int ks = 0; ks < 8; ++ks) {                                     \
      short8 bq2[2];                                                                       \
      _Pragma("unroll") for (int f = 0; f < 2; ++f)                                        \
          bq2[f] = PREAD(TB, f * 16 + lr, ks * 4 + lk);                                    \
      _Pragma("unroll") for (int i = 0; i < 2; ++i) _Pragma("unroll")                      \
          for (int j = 0; j < 2; ++j) sig[LP][i][j] =                                      \
              __builtin_amdgcn_mfma_f32_16x16x32_bf16(am2[i][ks], bq2[j], sig[LP][i][j], 0, 0, 0); \
    }                                                                                      \
    if (w == (LP) && lk == (lr >> 2)) {                                                    \
      _Pragma("unroll") for (int lf = 0; lf < 2; ++lf) {                                   \
        f32x4 v4 = sig[LP][lf][lf];                                                        \
        dsig[R + lf * 16 + lr] = v4[lr & 3];                                               \
      }                                                                                    \
    }                                                                                      \
  }

  // SB[0] holds m2th panel 0 (staged at cp==7; drained by that barrier)
  STAGE2(1) STEP1(0)
  __syncthreads();
  STAGE2(2) STEP1(1) STEP2(0)
  __syncthreads();
  STAGE2(3) STEP1(2) STEP2(1)
  __syncthreads();
  STAGE2(4) STEP1(3) STEP2(2)
  __syncthreads();
  STAGE2(5) STEP1(4) STEP2(3)
  __syncthreads();
  STAGE2(6) STEP1(5) STEP2(4)
  __syncthreads();
  STAGE2(7) STEP1(6) STEP2(5)
  __syncthreads();
  STEP1(7) STEP2(6)
  __syncthreads();
  STEP2(7)
  __syncthreads();
#undef STEP1
#undef STEP2
#undef STAGE2
#undef PREAD

  // ---------- c3 phase ----------
  if (tid < 256) {
    float ds = dsig[tid] + s2L[tid];
    float rs = rsqrtf(ds);
    float xb = tanhf(SQ2PI_F * h3bar[b * 256 + tid] * rs);
    x3bar[b * 256 + tid] = xb;
    float d = 1.f - xb * xb;
    c3L[tid] = d * rs;
    d3L[tid] = d;
  }
  __syncthreads();

  // ---------- epilogue: xcov3 from sig (transposed-symmetric store) ----------
#pragma unroll
  for (int lp = 0; lp < 8; ++lp) {
#pragma unroll
    for (int ifg = 0; ifg < 2; ++ifg) {
      int i0 = R + ifg * 16 + lk * 4;
#pragma unroll
      for (int lf = 0; lf < 2; ++lf) {
        int gl = lp * 32 + lf * 16 + lr;
        float cg = c3L[gl];
        f32x4 st;
#pragma unroll
        for (int e = 0; e < 4; ++e) {
          int i = i0 + e;
          float g = sig[lp][ifg][lf][e];
          if (i == gl) g += s2L[i];
          float v = SQ2PI_F * c3L[i] * cg * g;
          if (i == gl) v += d3L[i];
          st[e] = v;
        }
        *(f32x4*)(xcov3 + ((size_t)b << 16) + (size_t)gl * 256 + i0) = st;
      }
    }
  }
}

// final layer + log_softmax + loss + frac_correct. grid 4 x block 64
__global__ void k_final4(const float* __restrict__ x3bar, const float* __restrict__ mlast,
                         const float* __restrict__ thlast, const int* __restrict__ target,
                         float* __restrict__ hlast_out, float* __restrict__ logp_out,
                         float* __restrict__ loss_out, float* __restrict__ frac_out) {
  __shared__ float Wl[2560];
  int t = threadIdx.x;
  int r = blockIdx.x * 64 + t;
  for (int p = t; p < 2560; p += 64) Wl[p] = mlast[p];
  __syncthreads();
  float acc[10];
#pragma unroll
  for (int c = 0; c < 10; ++c) acc[c] = thlast[c];
  for (int j = 0; j < 256; ++j) {
    float xv = x3bar[r * 256 + j];
#pragma unroll
    for (int c = 0; c < 10; ++c) acc[c] = fmaf(xv, Wl[j * 10 + c], acc[c]);
  }
#pragma unroll
  for (int c = 0; c < 10; ++c) hlast_out[r * 10 + c] = acc[c];
  float mx = acc[0];
  int am = 0;
#pragma unroll
  for (int c = 1; c < 10; ++c)
    if (acc[c] > mx) { mx = acc[c]; am = c; }
  float se = 0.f;
#pragma unroll
  for (int c = 0; c < 10; ++c) se += expf(acc[c] - mx);
  float lse = logf(se);
#pragma unroll
  for (int c = 0; c < 10; ++c) logp_out[r * 10 + c] = acc[c] - mx - lse;
  int tg = target[r];
  float lossc = -(acc[tg] - mx - lse) * (1.f / 256.f);
  float corr = (am == tg) ? (1.f / 256.f) : 0.f;
#pragma unroll
  for (int off = 32; off > 0; off >>= 1) {
    lossc += __shfl_down(lossc, off);
    corr += __shfl_down(corr, off);
  }
  if (t == 0) {
    atomicAdd(loss_out, lossc);
    atomicAdd(frac_out, corr);
  }
}

// ------------------------------------------------------------------

extern "C" void kernel_launch(void* const* d_in, const int* in_sizes, int n_in,
                              void* d_out, int out_size, void* d_ws, size_t ws_size,
                              hipStream_t stream) {
  const float* x = (const float*)d_in[0];
  const int* target = (const int*)d_in[1];
  const float* w0 = (const float*)d_in[2];
  const float* w1 = (const float*)d_in[3];
  const float* w2 = (const float*)d_in[4];
  const float* wlast = (const float*)d_in[5];
  const float* th0 = (const float*)d_in[6];
  const float* th1 = (const float*)d_in[7];
  const float* th2 = (const float*)d_in[8];
  const float* thlast = (const float*)d_in[9];

  float* W = (float*)d_ws;
  size_t o = 0;
  auto alloc = [&](size_t n) { float* p = W + o; o += n; return p; };
  float* m0 = alloc(200704);
  float* m1 = alloc(65536);
  float* m2 = alloc(65536);
  float* mlast = alloc(2560);
  float* diagsig1 = alloc(256);  // zero-block start (768 floats, contiguous)
  float* s1 = alloc(256);
  float* s2 = alloc(256);
  float* x1bar = alloc(65536);
  float* d1 = alloc(65536);
  float* c2 = alloc(65536);
  float* d2p = alloc(65536);
  float* h3bar = alloc(65536);
  float* x3bar = alloc(65536);
  unsigned short* m1th = (unsigned short*)alloc(32768);  // 65536 bf16
  unsigned short* m2th = (unsigned short*)alloc(32768);  // 65536 bf16

  float* hlast = (float*)d_out;
  float* logp = hlast + 2560;
  float* xcov3_out = logp + 2560;
  float* loss = xcov3_out + 16777216;
  float* frac = loss + 1;

  // 1) prep
  k_prep<<<1309, 256, 0, stream>>>(w0, w1, w2, wlast, m0, m1, m1th, m2, m2th,
                                   mlast, diagsig1, loss);
  // 2) column sums
  k_colsums<<<15, 256, 0, stream>>>(m0, m1, m2, diagsig1, s1, s2);
  // 3) layer 1 (split-k, 512 thr)
  k_layer1<<<256, 512, 0, stream>>>(x, m0, diagsig1, th0, x1bar, d1);
  // 4) layer 2 (+h3, split-k, 512 thr)
  k_layer2<<<256, 512, 0, stream>>>(d1, x1bar, m1, m2, s1, th1, th2, c2, d2p, h3bar);
  // 5) fused sigma-chain (gload_lds-staged panels, zero in-loop lane loads)
  k_fused<<<256, 512, 0, stream>>>(m1th, m2th, d1, c2, d2p, s1, s2,
                                   h3bar, x3bar, xcov3_out);
  // 6) final layer + softmax + loss + acc
  k_final4<<<4, 64, 0, stream>>>(x3bar, mlast, thlast, target, hlast, logp, loss, frac);
}

// Round 11
// 131.183 us; speedup vs baseline: 4.4716x; 1.1915x over previous
//
#include <hip/hip_runtime.h>
#include <math.h>

#define SQ2PI_F 0.79788456f

typedef __attribute__((ext_vector_type(8))) short short8;
typedef __attribute__((ext_vector_type(4))) float f32x4;
typedef __attribute__((ext_vector_type(4))) unsigned short u16x4;
typedef __attribute__((address_space(1))) unsigned int gas_u32;
typedef __attribute__((address_space(3))) unsigned int las_u32;

__device__ inline unsigned short bf16rne(float x) {
  unsigned int u = __float_as_uint(x);
  u += 0x7fffu + ((u >> 16) & 1u);
  return (unsigned short)(u >> 16);
}
__device__ inline float bf2f(unsigned short u) {
  return __uint_as_float(((unsigned int)u) << 16);
}

// ------------------------------------------------------------------
// fused prep: means (+bf16 transposes), zero loss/frac
// blocks [0,784) m0 | [784,1040) m1+m1th | [1040,1296) m2+m2th |
// [1296,1306) mlast (+loss/frac zero)
// ------------------------------------------------------------------
__global__ void k_prep(const float* __restrict__ w0, const float* __restrict__ w1,
                       const float* __restrict__ w2, const float* __restrict__ wlast,
                       float* __restrict__ m0, float* __restrict__ m1,
                       unsigned short* __restrict__ m1th, float* __restrict__ m2,
                       unsigned short* __restrict__ m2th, float* __restrict__ mlast,
                       float* __restrict__ lf) {
  int b = blockIdx.x, t = threadIdx.x;
  if (b < 784) {
    int i = b * 256 + t;
    m0[i] = tanhf(0.5f * w0[i]);
  } else if (b < 1040) {
    int j = b - 784;
    float v = tanhf(0.5f * w1[j * 256 + t]);
    m1[j * 256 + t] = v;
    m1th[t * 256 + j] = bf16rne(v);   // m1th[r][k] = m1[k][r]
  } else if (b < 1296) {
    int j = b - 1040;
    float v = tanhf(0.5f * w2[j * 256 + t]);
    m2[j * 256 + t] = v;
    m2th[t * 256 + j] = bf16rne(v);   // m2th[i][j] = m2[j][i]
  } else {
    int i = (b - 1296) * 256 + t;
    if (i < 2560) mlast[i] = tanhf(0.5f * wlast[i]);
    if (b == 1296 && t < 2) lf[t] = 0.f;
  }
}

// layer 1: block=row r, 512 thr split-k; diagsig1 folded in (same m0 loads)
__global__ void k_layer1(const float* __restrict__ x, const float* __restrict__ m0,
                         const float* __restrict__ th0,
                         float* __restrict__ x1bar, float* __restrict__ d1) {
  __shared__ float xr[784];
  __shared__ float ph[256], pd[256];
  int r = blockIdx.x, t = threadIdx.x;
  int j = t & 255, h = t >> 8;
  for (int p = t; p < 784; p += 512) xr[p] = x[r * 784 + p];
  __syncthreads();
  float acch = 0.f, accd = 0.f;
  int k0 = h * 392, k1 = k0 + 392;
#pragma unroll 8
  for (int k = k0; k < k1; ++k) {
    float mm = m0[k * 256 + j];
    acch = fmaf(xr[k], mm, acch);
    accd = fmaf(-mm, mm, accd + 1.f);
  }
  if (h) { ph[j] = acch; pd[j] = accd; }
  __syncthreads();
  if (!h) {
    acch += ph[j];
    accd += pd[j];
    float rs = rsqrtf(accd);
    float xb = tanhf(SQ2PI_F * (acch + th0[j]) * rs);
    x1bar[r * 256 + j] = xb;
    d1[r * 256 + j] = 1.f - xb * xb;
  }
}

// layer-2 pass + h3; s1/s2 folded in (same m1/m2 loads; block 0 publishes)
__global__ void k_layer2(const float* __restrict__ d1, const float* __restrict__ x1bar,
                         const float* __restrict__ m1, const float* __restrict__ m2,
                         const float* __restrict__ th1, const float* __restrict__ th2,
                         float* __restrict__ c2, float* __restrict__ d2p,
                         float* __restrict__ h3bar,
                         float* __restrict__ s1g, float* __restrict__ s2g) {
  __shared__ float pd[256], ph[256], ps[256], sx[256], p3[256], q2[256];
  int r = blockIdx.x, t = threadIdx.x;
  int i = t & 255, h = t >> 8;
  int j0 = h * 128, j1 = j0 + 128;
  float accd = 0.f, acch = 0.f, accs = 0.f;
  for (int j = j0; j < j1; ++j) {
    float mm = m1[j * 256 + i];
    accd = fmaf(d1[r * 256 + j] * mm, mm, accd);
    acch = fmaf(x1bar[r * 256 + j], mm, acch);
    accs = fmaf(-mm, mm, accs + 1.f);
  }
  if (h) { pd[i] = accd; ph[i] = acch; ps[i] = accs; }
  __syncthreads();
  if (!h) {
    accd += pd[i];
    acch += ph[i];
    accs += ps[i];                       // = s1[i]
    float rs = rsqrtf(accd + accs);
    float xb = tanhf(SQ2PI_F * (acch + th1[i]) * rs);
    float d = 1.f - xb * xb;
    c2[r * 256 + i] = d * rs;
    d2p[r * 256 + i] = d;
    sx[i] = xb;
    if (r == 0) s1g[i] = accs;
  }
  __syncthreads();
  float acc3 = 0.f, acc2 = 0.f;
  for (int j = j0; j < j1; ++j) {
    float mm = m2[j * 256 + i];
    acc3 = fmaf(sx[j], mm, acc3);
    acc2 = fmaf(-mm, mm, acc2 + 1.f);
  }
  if (h) { p3[i] = acc3; q2[i] = acc2; }
  __syncthreads();
  if (!h) {
    h3bar[r * 256 + i] = acc3 + p3[i] + th2[i];
    if (r == 0) s2g[i] = acc2 + q2[i];   // = s2[i]
  }
}

// ------------------------------------------------------------------
// k_fused: identical to round 10 except __launch_bounds__(512) — the
// (512,2) min-waves clamp forced a 128-VGPR cap and ~20MB of scratch
// spill traffic; occupancy is grid-limited (1 block/CU) so the clamp
// bought nothing. All in-loop weight operands via global_load_lds
// staged panels (double-buffered, prefetched); af_w/afX/am2 in regs.
// ------------------------------------------------------------------
__global__ __launch_bounds__(512) void k_fused(
    const unsigned short* __restrict__ m1th, const unsigned short* __restrict__ m2th,
    const float* __restrict__ d1, const float* __restrict__ c2,
    const float* __restrict__ d2p, const float* __restrict__ s1,
    const float* __restrict__ s2, const float* __restrict__ h3bar,
    float* __restrict__ x3bar, float* __restrict__ xcov3) {
  __shared__ __align__(16) unsigned short SB[2][8192];  // staged weight panels
  __shared__ __align__(16) unsigned short XB[2][8192];  // exchange panels
  __shared__ float c2L[256], d2pL[256], s1L[256], s2L[256];
  __shared__ float dsig[256], c3L[256], d3L[256];

  const int b = blockIdx.x;
  const int tid = threadIdx.x;
  const int l = tid & 63, w = tid >> 6;
  const int lr = l & 15, lk = l >> 4;
  const int R = w * 32;

  auto stage_panel = [&](const unsigned short* gsrc, unsigned short* sb) {
#pragma unroll
    for (int q = 0; q < 2; ++q) {
      int rl = q * 16 + w * 2 + (l >> 5);
      int ch = l & 31;
      const unsigned short* src = gsrc + rl * 256 + ((ch ^ (rl & 7)) << 3);
      unsigned short* dst = sb + (q * 16 + w * 2) * 256;
      __builtin_amdgcn_global_load_lds((const gas_u32*)src, (las_u32*)dst, 16, 0, 0);
    }
  };

#define PREAD(SBASE, p, kc)                                   \
  (*(const short8*)((const char*)(SBASE) + ((p) << 9) +      \
                    ((unsigned)((((kc) ^ ((p) & 7))) << 4))))

  stage_panel(m1th, SB[0]);

  if (tid < 256) {
    c2L[tid] = c2[b * 256 + tid];
    d2pL[tid] = d2p[b * 256 + tid];
    s1L[tid] = s1[tid];
    s2L[tid] = s2[tid];
  }

  const float* d1b = d1 + b * 256;

  short8 af_w[2][8];
#pragma unroll
  for (int ks = 0; ks < 8; ++ks) {
    f32x4 dv0 = *(const f32x4*)(d1b + ks * 32 + lk * 8);
    f32x4 dv1 = *(const f32x4*)(d1b + ks * 32 + lk * 8 + 4);
#pragma unroll
    for (int f = 0; f < 2; ++f) {
      short8 mv = *(const short8*)(m1th + (size_t)(R + f * 16 + lr) * 256 + ks * 32 + lk * 8);
#pragma unroll
      for (int e = 0; e < 4; ++e) {
        af_w[f][ks][e] = (short)bf16rne(bf2f((unsigned short)mv[e]) * dv0[e]);
        af_w[f][ks][e + 4] = (short)bf16rne(bf2f((unsigned short)mv[e + 4]) * dv1[e]);
      }
    }
  }
  __syncthreads();  // drains gload_lds (SB[0]) + c2L visibility

  short8 afX[2][8];

  // ---------- phase 1: xcov2 panels from staged m1th, exchange via XB ----------
#pragma unroll
  for (int cp = 0; cp < 8; ++cp) {
    if (cp < 7)
      stage_panel(m1th + (size_t)(cp + 1) * 32 * 256, SB[(cp + 1) & 1]);
    else
      stage_panel(m2th, SB[0]);
    const unsigned short* sbc = SB[cp & 1];
    f32x4 acc[2][2];
#pragma unroll
    for (int i = 0; i < 2; ++i)
#pragma unroll
      for (int j = 0; j < 2; ++j) acc[i][j] = {0.f, 0.f, 0.f, 0.f};
#pragma unroll
    for (int ks = 0; ks < 8; ++ks) {
      short8 bq[2];
#pragma unroll
      for (int f = 0; f < 2; ++f) bq[f] = PREAD(sbc, f * 16 + lr, ks * 4 + lk);
#pragma unroll
      for (int i = 0; i < 2; ++i)
#pragma unroll
        for (int j = 0; j < 2; ++j)
          acc[i][j] = __builtin_amdgcn_mfma_f32_16x16x32_bf16(af_w[i][ks], bq[j], acc[i][j], 0, 0, 0);
    }
    char* XP = (char*)XB[cp & 1];
#pragma unroll
    for (int i = 0; i < 2; ++i) {
      int r0 = R + i * 16 + lk * 4;
#pragma unroll
      for (int j = 0; j < 2; ++j) {
        int p = j * 16 + lr;
        int cc = cp * 32 + p;
        float c2c = c2L[cc];
        u16x4 st;
#pragma unroll
        for (int e = 0; e < 4; ++e) {
          int r = r0 + e;
          float g = acc[i][j][e];
          if (r == cc) g += s1L[r];
          float v = SQ2PI_F * c2L[r] * c2c * g;
          if (r == cc) v += d2pL[r];
          st[e] = bf16rne(v);
        }
        *(u16x4*)(XP + (p << 9) + (((unsigned)(r0 << 1)) ^ ((p & 7) << 4))) = st;
      }
    }
    __syncthreads();
    if (w == cp) {
#pragma unroll
      for (int f = 0; f < 2; ++f) {
        int p2 = f * 16 + lr;
#pragma unroll
        for (int ks = 0; ks < 8; ++ks)
          afX[f][ks] = PREAD(XP, p2, ks * 4 + lk);
      }
    }
  }

  // hoist wave's own 32 m2th rows (STEP2 A-operand; loop-invariant)
  short8 am2[2][8];
#pragma unroll
  for (int f = 0; f < 2; ++f)
#pragma unroll
    for (int ks = 0; ks < 8; ++ks)
      am2[f][ks] = *(const short8*)(m2th + (size_t)(R + f * 16 + lr) * 256 + ks * 32 + lk * 8);

  // ---------- loop B: pipelined t3-panel / sigma3 accumulation ----------
  f32x4 sig[8][2][2];
#pragma unroll
  for (int lp = 0; lp < 8; ++lp)
#pragma unroll
    for (int i = 0; i < 2; ++i)
#pragma unroll
      for (int j = 0; j < 2; ++j) sig[lp][i][j] = {0.f, 0.f, 0.f, 0.f};

#define STAGE2(N) stage_panel(m2th + (size_t)(N) * 32 * 256, SB[(N) & 1]);

#define STEP1(LP)                                                                          \
  {                                                                                        \
    const unsigned short* sb1 = SB[(LP) & 1];                                              \
    char* TB = (char*)XB[(LP) & 1];                                                        \
    f32x4 at[2][2];                                                                        \
    _Pragma("unroll") for (int i = 0; i < 2; ++i) _Pragma("unroll")                        \
        for (int j = 0; j < 2; ++j) at[i][j] = {0.f, 0.f, 0.f, 0.f};                       \
    _Pragma("unroll") for (int ks = 0; ks < 8; ++ks) {                                     \
      short8 bq[2];                                                                        \
      _Pragma("unroll") for (int f = 0; f < 2; ++f)                                        \
          bq[f] = PREAD(sb1, f * 16 + lr, ks * 4 + lk);                                    \
      _Pragma("unroll") for (int i = 0; i < 2; ++i) _Pragma("unroll")                      \
          for (int j = 0; j < 2; ++j) at[i][j] =                                           \
              __builtin_amdgcn_mfma_f32_16x16x32_bf16(afX[i][ks], bq[j], at[i][j], 0, 0, 0); \
    }                                                                                      \
    _Pragma("unroll") for (int i = 0; i < 2; ++i) {                                        \
      int j0 = R + i * 16 + lk * 4;                                                        \
      _Pragma("unroll") for (int jf = 0; jf < 2; ++jf) {                                   \
        int p = jf * 16 + lr;                                                              \
        u16x4 st;                                                                          \
        _Pragma("unroll") for (int e = 0; e < 4; ++e) st[e] = bf16rne(at[i][jf][e]);       \
        *(u16x4*)(TB + (p << 9) + (((unsigned)(j0 << 1)) ^ ((p & 7) << 4))) = st;          \
      }                                                                                    \
    }                                                                                      \
  }

#define STEP2(LP)                                                                          \
  {                                                                                        \
    const char* TB = (const char*)XB[(LP) & 1];                                            \
    _Pragma("unroll") for (int ks = 0; ks < 8; ++ks) {                                     \
      short8 bq2[2];                                                                       \
      _Pragma("unroll") for (int f = 0; f < 2; ++f)                                        \
          bq2[f] = PREAD(TB, f * 16 + lr, ks * 4 + lk);                                    \
      _Pragma("unroll") for (int i = 0; i < 2; ++i) _Pragma("unroll")                      \
          for (int j = 0; j < 2; ++j) sig[LP][i][j] =                                      \
              __builtin_amdgcn_mfma_f32_16x16x32_bf16(am2[i][ks], bq2[j], sig[LP][i][j], 0, 0, 0); \
    }                                                                                      \
    if (w == (LP) && lk == (lr >> 2)) {                                                    \
      _Pragma("unroll") for (int lf = 0; lf < 2; ++lf) {                                   \
        f32x4 v4 = sig[LP][lf][lf];                                                        \
        dsig[R + lf * 16 + lr] = v4[lr & 3];                                               \
      }                                                                                    \
    }                                                                                      \
  }

  STAGE2(1) STEP1(0)
  __syncthreads();
  STAGE2(2) STEP1(1) STEP2(0)
  __syncthreads();
  STAGE2(3) STEP1(2) STEP2(1)
  __syncthreads();
  STAGE2(4) STEP1(3) STEP2(2)
  __syncthreads();
  STAGE2(5) STEP1(4) STEP2(3)
  __syncthreads();
  STAGE2(6) STEP1(5) STEP2(4)
  __syncthreads();
  STAGE2(7) STEP1(6) STEP2(5)
  __syncthreads();
  STEP1(7) STEP2(6)
  __syncthreads();
  STEP2(7)
  __syncthreads();
#undef STEP1
#undef STEP2
#undef STAGE2
#undef PREAD

  // ---------- c3 phase ----------
  if (tid < 256) {
    float ds = dsig[tid] + s2L[tid];
    float rs = rsqrtf(ds);
    float xb = tanhf(SQ2PI_F * h3bar[b * 256 + tid] * rs);
    x3bar[b * 256 + tid] = xb;
    float d = 1.f - xb * xb;
    c3L[tid] = d * rs;
    d3L[tid] = d;
  }
  __syncthreads();

  // ---------- epilogue: xcov3 from sig (transposed-symmetric store) ----------
#pragma unroll
  for (int lp = 0; lp < 8; ++lp) {
#pragma unroll
    for (int ifg = 0; ifg < 2; ++ifg) {
      int i0 = R + ifg * 16 + lk * 4;
#pragma unroll
      for (int lf = 0; lf < 2; ++lf) {
        int gl = lp * 32 + lf * 16 + lr;
        float cg = c3L[gl];
        f32x4 st;
#pragma unroll
        for (int e = 0; e < 4; ++e) {
          int i = i0 + e;
          float g = sig[lp][ifg][lf][e];
          if (i == gl) g += s2L[i];
          float v = SQ2PI_F * c3L[i] * cg * g;
          if (i == gl) v += d3L[i];
          st[e] = v;
        }
        *(f32x4*)(xcov3 + ((size_t)b << 16) + (size_t)gl * 256 + i0) = st;
      }
    }
  }
}

// final layer + log_softmax + loss + frac_correct. grid 4 x block 64
__global__ void k_final4(const float* __restrict__ x3bar, const float* __restrict__ mlast,
                         const float* __restrict__ thlast, const int* __restrict__ target,
                         float* __restrict__ hlast_out, float* __restrict__ logp_out,
                         float* __restrict__ loss_out, float* __restrict__ frac_out) {
  __shared__ float Wl[2560];
  int t = threadIdx.x;
  int r = blockIdx.x * 64 + t;
  for (int p = t; p < 2560; p += 64) Wl[p] = mlast[p];
  __syncthreads();
  float acc[10];
#pragma unroll
  for (int c = 0; c < 10; ++c) acc[c] = thlast[c];
  for (int j = 0; j < 256; ++j) {
    float xv = x3bar[r * 256 + j];
#pragma unroll
    for (int c = 0; c < 10; ++c) acc[c] = fmaf(xv, Wl[j * 10 + c], acc[c]);
  }
#pragma unroll
  for (int c = 0; c < 10; ++c) hlast_out[r * 10 + c] = acc[c];
  float mx = acc[0];
  int am = 0;
#pragma unroll
  for (int c = 1; c < 10; ++c)
    if (acc[c] > mx) { mx = acc[c]; am = c; }
  float se = 0.f;
#pragma unroll
  for (int c = 0; c < 10; ++c) se += expf(acc[c] - mx);
  float lse = logf(se);
#pragma unroll
  for (int c = 0; c < 10; ++c) logp_out[r * 10 + c] = acc[c] - mx - lse;
  int tg = target[r];
  float lossc = -(acc[tg] - mx - lse) * (1.f / 256.f);
  float corr = (am == tg) ? (1.f / 256.f) : 0.f;
#pragma unroll
  for (int off = 32; off > 0; off >>= 1) {
    lossc += __shfl_down(lossc, off);
    corr += __shfl_down(corr, off);
  }
  if (t == 0) {
    atomicAdd(loss_out, lossc);
    atomicAdd(frac_out, corr);
  }
}

// ------------------------------------------------------------------

extern "C" void kernel_launch(void* const* d_in, const int* in_sizes, int n_in,
                              void* d_out, int out_size, void* d_ws, size_t ws_size,
                              hipStream_t stream) {
  const float* x = (const float*)d_in[0];
  const int* target = (const int*)d_in[1];
  const float* w0 = (const float*)d_in[2];
  const float* w1 = (const float*)d_in[3];
  const float* w2 = (const float*)d_in[4];
  const float* wlast = (const float*)d_in[5];
  const float* th0 = (const float*)d_in[6];
  const float* th1 = (const float*)d_in[7];
  const float* th2 = (const float*)d_in[8];
  const float* thlast = (const float*)d_in[9];

  float* W = (float*)d_ws;
  size_t o = 0;
  auto alloc = [&](size_t n) { float* p = W + o; o += n; return p; };
  float* m0 = alloc(200704);
  float* m1 = alloc(65536);
  float* m2 = alloc(65536);
  float* mlast = alloc(2560);
  float* s1 = alloc(256);
  float* s2 = alloc(256);
  float* x1bar = alloc(65536);
  float* d1 = alloc(65536);
  float* c2 = alloc(65536);
  float* d2p = alloc(65536);
  float* h3bar = alloc(65536);
  float* x3bar = alloc(65536);
  unsigned short* m1th = (unsigned short*)alloc(32768);  // 65536 bf16
  unsigned short* m2th = (unsigned short*)alloc(32768);  // 65536 bf16

  float* hlast = (float*)d_out;
  float* logp = hlast + 2560;
  float* xcov3_out = logp + 2560;
  float* loss = xcov3_out + 16777216;
  float* frac = loss + 1;

  // 1) prep (means + transposes + zero loss/frac)
  k_prep<<<1306, 256, 0, stream>>>(w0, w1, w2, wlast, m0, m1, m1th, m2, m2th,
                                   mlast, loss);
  // 2) layer 1 (split-k, diagsig1 folded)
  k_layer1<<<256, 512, 0, stream>>>(x, m0, th0, x1bar, d1);
  // 3) layer 2 (+h3, s1/s2 folded, split-k)
  k_layer2<<<256, 512, 0, stream>>>(d1, x1bar, m1, m2, th1, th2, c2, d2p,
                                    h3bar, s1, s2);
  // 4) fused sigma-chain (spill-free: no min-waves clamp)
  k_fused<<<256, 512, 0, stream>>>(m1th, m2th, d1, c2, d2p, s1, s2,
                                   h3bar, x3bar, xcov3_out);
  // 5) final layer + softmax + loss + acc
  k_final4<<<4, 64, 0, stream>>>(x3bar, mlast, thlast, target, hlast, logp, loss, frac);
}